// Round 1
// baseline (625.489 us; speedup 1.0000x reference)
//
#include <hip/hip_runtime.h>
#include <hip/hip_bf16.h>

#define NE 1600000
#define NN 100000
#define H 64
#define ED 16

// LDS row strides (elements). All chosen so row stride in bytes is a
// multiple of 16 (ds_read_b128 alignment) and dword stride % 32 walks
// banks (2-way max conflict = free on gfx950).
#define K1S 168   // K padded 144 -> 160 used, 168 stride
#define K2S 72    // K = 64 used, 72 stride
#define K3S 136   // K = 128 used, 136 stride

typedef __attribute__((ext_vector_type(8))) short short8;
typedef __attribute__((ext_vector_type(4))) float floatx4;

__device__ __forceinline__ unsigned short f2bf(float f) {
    union { float f; unsigned u; } v; v.f = f;
    unsigned r = v.u + 0x7fff + ((v.u >> 16) & 1);
    return (unsigned short)(r >> 16);
}

__device__ __forceinline__ float silu(float x) {
    return x / (1.0f + __expf(-x));
}

// ---------------- prep: x -> bf16, weights -> transposed padded bf16 ----
__global__ void prep_kernel(const float* __restrict__ x,
                            const float* __restrict__ W1,
                            const float* __restrict__ W2,
                            const float* __restrict__ W3,
                            unsigned short* __restrict__ xb,
                            unsigned short* __restrict__ W1T,
                            unsigned short* __restrict__ W2T,
                            unsigned short* __restrict__ W3T) {
    int tid = blockIdx.x * blockDim.x + threadIdx.x;
    int nt = gridDim.x * blockDim.x;
    // x: N*H floats -> bf16 (vectorized 4-wide)
    const float4* xv = (const float4*)x;
    ushort4* xbv = (ushort4*)xb;
    for (int i = tid; i < NN * H / 4; i += nt) {
        float4 v = xv[i];
        ushort4 o;
        o.x = f2bf(v.x); o.y = f2bf(v.y); o.z = f2bf(v.z); o.w = f2bf(v.w);
        xbv[i] = o;
    }
    // W1T[n][k] = W1[k][n], k<144 else 0
    for (int i = tid; i < 64 * K1S; i += nt) {
        int n = i / K1S, k = i % K1S;
        W1T[i] = (k < 144) ? f2bf(W1[k * 64 + n]) : (unsigned short)0;
    }
    for (int i = tid; i < 64 * K2S; i += nt) {
        int n = i / K2S, k = i % K2S;
        W2T[i] = (k < 64) ? f2bf(W2[k * 64 + n]) : (unsigned short)0;
    }
    for (int i = tid; i < 64 * K3S; i += nt) {
        int n = i / K3S, k = i % K3S;
        W3T[i] = (k < 128) ? f2bf(W3[k * 64 + n]) : (unsigned short)0;
    }
}

// ---------------- edge MLP + scatter-add --------------------------------
__global__ __launch_bounds__(256) void edge_kernel(
    const unsigned short* __restrict__ xb,
    const int* __restrict__ ei,
    const float* __restrict__ ea,
    const unsigned short* __restrict__ W1T,
    const unsigned short* __restrict__ W2T,
    const float* __restrict__ b1,
    const float* __restrict__ b2,
    float* __restrict__ agg) {
    __shared__ unsigned short sW1[64 * K1S];
    __shared__ unsigned short sW2[64 * K2S];
    __shared__ unsigned short sA[64 * K1S];
    __shared__ unsigned short sH[64 * K2S];
    __shared__ int sDst[64];

    int t = threadIdx.x;
    int e0 = blockIdx.x * 64;

    // stage pre-packed weights (contiguous uint4 copies)
    {
        const uint4* w1v = (const uint4*)W1T;
        uint4* s1v = (uint4*)sW1;
        for (int i = t; i < 64 * K1S * 2 / 16; i += 256) s1v[i] = w1v[i];
        const uint4* w2v = (const uint4*)W2T;
        uint4* s2v = (uint4*)sW2;
        for (int i = t; i < 64 * K2S * 2 / 16; i += 256) s2v[i] = w2v[i];
    }

    // gather A tile: 4 threads per edge
    {
        int eL = t >> 2;          // local edge 0..63
        int sub = t & 3;          // 0..3
        int e = e0 + eL;
        int srcN = ei[e];
        int dstN = ei[NE + e];
        if (sub == 0) sDst[eL] = dstN;
        const uint4* xs = (const uint4*)(xb + (size_t)srcN * H);
        const uint4* xd = (const uint4*)(xb + (size_t)dstN * H);
        uint4* arow = (uint4*)(sA + eL * K1S);    // 336B stride, 16B aligned
        arow[sub * 2]     = xs[sub * 2];
        arow[sub * 2 + 1] = xs[sub * 2 + 1];
        arow[8 + sub * 2]     = xd[sub * 2];
        arow[8 + sub * 2 + 1] = xd[sub * 2 + 1];
        // edge_attr: 16 fp32 -> bf16
        const float4* eav = (const float4*)(ea + (size_t)e * ED);
        float4 v = eav[sub];
        unsigned short* erow = sA + eL * K1S + 128 + sub * 4;
        erow[0] = f2bf(v.x); erow[1] = f2bf(v.y);
        erow[2] = f2bf(v.z); erow[3] = f2bf(v.w);
        // zero pad k = 144..159
        unsigned short* zp = sA + eL * K1S + 144 + sub * 4;
        zp[0] = 0; zp[1] = 0; zp[2] = 0; zp[3] = 0;
    }
    __syncthreads();

    int w = t >> 6;        // wave 0..3 -> edge rows w*16..w*16+15
    int lane = t & 63;
    int m = lane & 15;     // row (A) / col (B,C) within tile
    int q = lane >> 4;     // quad 0..3

    // GEMM1: [16 x 160] @ [160 x 64]
    floatx4 acc[4];
    #pragma unroll
    for (int i = 0; i < 4; i++) acc[i] = (floatx4){0.f, 0.f, 0.f, 0.f};
    int arowi = w * 16 + m;
    #pragma unroll
    for (int kt = 0; kt < 5; kt++) {
        short8 a = *(const short8*)(sA + arowi * K1S + kt * 32 + q * 8);
        #pragma unroll
        for (int tt = 0; tt < 4; tt++) {
            short8 b = *(const short8*)(sW1 + (tt * 16 + m) * K1S + kt * 32 + q * 8);
            acc[tt] = __builtin_amdgcn_mfma_f32_16x16x32_bf16(a, b, acc[tt], 0, 0, 0);
        }
    }

    // epilogue 1: bias + SiLU -> sH (A-layout for GEMM2)
    #pragma unroll
    for (int tt = 0; tt < 4; tt++) {
        int c = tt * 16 + m;
        float bias = b1[c];
        #pragma unroll
        for (int r = 0; r < 4; r++) {
            float hv = silu(acc[tt][r] + bias);
            sH[(w * 16 + q * 4 + r) * K2S + c] = f2bf(hv);
        }
    }
    __syncthreads();

    // GEMM2: [16 x 64] @ [64 x 64]
    floatx4 acc2[4];
    #pragma unroll
    for (int i = 0; i < 4; i++) acc2[i] = (floatx4){0.f, 0.f, 0.f, 0.f};
    #pragma unroll
    for (int kt = 0; kt < 2; kt++) {
        short8 a = *(const short8*)(sH + arowi * K2S + kt * 32 + q * 8);
        #pragma unroll
        for (int tt = 0; tt < 4; tt++) {
            short8 b = *(const short8*)(sW2 + (tt * 16 + m) * K2S + kt * 32 + q * 8);
            acc2[tt] = __builtin_amdgcn_mfma_f32_16x16x32_bf16(a, b, acc2[tt], 0, 0, 0);
        }
    }

    // epilogue 2: bias + SiLU + scatter-add
    #pragma unroll
    for (int tt = 0; tt < 4; tt++) {
        int c = tt * 16 + m;
        float bias = b2[c];
        #pragma unroll
        for (int r = 0; r < 4; r++) {
            float mv = silu(acc2[tt][r] + bias);
            int row = w * 16 + q * 4 + r;
            atomicAdd(&agg[(size_t)sDst[row] * H + c], mv);
        }
    }
}

// ---------------- node MLP ----------------------------------------------
__global__ __launch_bounds__(256) void node_kernel(
    const unsigned short* __restrict__ xb,
    const float* __restrict__ agg,
    const unsigned short* __restrict__ W3T,
    const float* __restrict__ b3,
    float* __restrict__ out) {
    __shared__ unsigned short sW3[64 * K3S];
    __shared__ unsigned short sA[64 * K3S];

    int t = threadIdx.x;
    int n0 = blockIdx.x * 64;

    {
        const uint4* wv = (const uint4*)W3T;
        uint4* sv = (uint4*)sW3;
        for (int i = t; i < 64 * K3S * 2 / 16; i += 256) sv[i] = wv[i];
    }

    // build A rows: [x_bf16 (64) | agg->bf16 (64) | pad]
    {
        int nL = t >> 2, sub = t & 3;
        int node = n0 + nL;
        uint4* arow = (uint4*)(sA + nL * K3S);   // 272B stride
        if (node < NN) {
            const uint4* xs = (const uint4*)(xb + (size_t)node * H);
            arow[sub * 2]     = xs[sub * 2];
            arow[sub * 2 + 1] = xs[sub * 2 + 1];
            const float4* av = (const float4*)(agg + (size_t)node * H);
            unsigned short tmp[16];
            #pragma unroll
            for (int j = 0; j < 4; j++) {
                float4 v = av[sub * 4 + j];
                tmp[j * 4 + 0] = f2bf(v.x); tmp[j * 4 + 1] = f2bf(v.y);
                tmp[j * 4 + 2] = f2bf(v.z); tmp[j * 4 + 3] = f2bf(v.w);
            }
            uint4* drow = (uint4*)(sA + nL * K3S + 64 + sub * 16);
            drow[0] = ((const uint4*)tmp)[0];
            drow[1] = ((const uint4*)tmp)[1];
        } else {
            uint4 z = {0, 0, 0, 0};
            arow[sub * 2] = z; arow[sub * 2 + 1] = z;
            uint4* drow = (uint4*)(sA + nL * K3S + 64 + sub * 16);
            drow[0] = z; drow[1] = z;
        }
    }
    __syncthreads();

    int w = t >> 6;
    int lane = t & 63;
    int m = lane & 15;
    int q = lane >> 4;

    floatx4 acc[4];
    #pragma unroll
    for (int i = 0; i < 4; i++) acc[i] = (floatx4){0.f, 0.f, 0.f, 0.f};
    int arowi = w * 16 + m;
    #pragma unroll
    for (int kt = 0; kt < 4; kt++) {
        short8 a = *(const short8*)(sA + arowi * K3S + kt * 32 + q * 8);
        #pragma unroll
        for (int tt = 0; tt < 4; tt++) {
            short8 b = *(const short8*)(sW3 + (tt * 16 + m) * K3S + kt * 32 + q * 8);
            acc[tt] = __builtin_amdgcn_mfma_f32_16x16x32_bf16(a, b, acc[tt], 0, 0, 0);
        }
    }

    #pragma unroll
    for (int tt = 0; tt < 4; tt++) {
        int c = tt * 16 + m;
        float bias = b3[c];
        #pragma unroll
        for (int r = 0; r < 4; r++) {
            int row = w * 16 + q * 4 + r;
            int node = n0 + row;
            if (node < NN) {
                out[(size_t)node * H + c] = silu(acc[tt][r] + bias);
            }
        }
    }
}

extern "C" void kernel_launch(void* const* d_in, const int* in_sizes, int n_in,
                              void* d_out, int out_size, void* d_ws, size_t ws_size,
                              hipStream_t stream) {
    const float* x  = (const float*)d_in[0];
    const int*   ei = (const int*)d_in[1];
    const float* ea = (const float*)d_in[2];
    const float* W1 = (const float*)d_in[3];
    const float* b1 = (const float*)d_in[4];
    const float* W2 = (const float*)d_in[5];
    const float* b2 = (const float*)d_in[6];
    const float* W3 = (const float*)d_in[7];
    const float* b3 = (const float*)d_in[8];
    float* out = (float*)d_out;

    char* ws = (char*)d_ws;
    float* agg = (float*)ws;                                   // N*H fp32 = 25.6 MB
    unsigned short* xb  = (unsigned short*)(ws + 25600000);     // N*H bf16 = 12.8 MB
    unsigned short* W1T = (unsigned short*)(ws + 25600000 + 12800000);
    unsigned short* W2T = W1T + 64 * K1S;
    unsigned short* W3T = W2T + 64 * K2S;

    hipMemsetAsync(agg, 0, (size_t)NN * H * sizeof(float), stream);
    prep_kernel<<<2048, 256, 0, stream>>>(x, W1, W2, W3, xb, W1T, W2T, W3T);
    edge_kernel<<<NE / 64, 256, 0, stream>>>(xb, ei, ea, W1T, W2T, b1, b2, agg);
    node_kernel<<<(NN + 63) / 64, 256, 0, stream>>>(xb, agg, W3T, b3, out);
}

// Round 2
// 571.021 us; speedup vs baseline: 1.0954x; 1.0954x over previous
//
#include <hip/hip_runtime.h>
#include <hip/hip_bf16.h>

#define NE 1600000
#define NN 100000
#define H 64
#define ED 16
#define NT (NE / 64)        // 25000 edge tiles
#define NB1 391             // ceil(NN/256) scan blocks

#define K1S 168   // bf16 LDS row stride, GEMM1 A/B (K padded 144->160)
#define K2S 72    // bf16 row stride, h buffer (K=64)
#define K3S 136   // bf16 row stride, node GEMM (K=128)
#define MS  66    // fp32 row stride for message buffer (conflict-free)

typedef __attribute__((ext_vector_type(8))) short short8;
typedef __attribute__((ext_vector_type(4))) float floatx4;

__device__ __forceinline__ unsigned short f2bf(float f) {
    union { float f; unsigned u; } v; v.f = f;
    unsigned r = v.u + 0x7fff + ((v.u >> 16) & 1);
    return (unsigned short)(r >> 16);
}

__device__ __forceinline__ float silu(float x) {
    return x / (1.0f + __expf(-x));
}

// ---------------- prep: x -> bf16, weights -> transposed padded bf16 ----
__global__ void prep_kernel(const float* __restrict__ x,
                            const float* __restrict__ W1,
                            const float* __restrict__ W2,
                            const float* __restrict__ W3,
                            unsigned short* __restrict__ xb,
                            unsigned short* __restrict__ W1T,
                            unsigned short* __restrict__ W2T,
                            unsigned short* __restrict__ W3T) {
    int tid = blockIdx.x * blockDim.x + threadIdx.x;
    int nt = gridDim.x * blockDim.x;
    const float4* xv = (const float4*)x;
    ushort4* xbv = (ushort4*)xb;
    for (int i = tid; i < NN * H / 4; i += nt) {
        float4 v = xv[i];
        ushort4 o;
        o.x = f2bf(v.x); o.y = f2bf(v.y); o.z = f2bf(v.z); o.w = f2bf(v.w);
        xbv[i] = o;
    }
    for (int i = tid; i < 64 * K1S; i += nt) {
        int n = i / K1S, k = i % K1S;
        W1T[i] = (k < 144) ? f2bf(W1[k * 64 + n]) : (unsigned short)0;
    }
    for (int i = tid; i < 64 * K2S; i += nt) {
        int n = i / K2S, k = i % K2S;
        W2T[i] = (k < 64) ? f2bf(W2[k * 64 + n]) : (unsigned short)0;
    }
    for (int i = tid; i < 64 * K3S; i += nt) {
        int n = i / K3S, k = i % K3S;
        W3T[i] = (k < 128) ? f2bf(W3[k * 64 + n]) : (unsigned short)0;
    }
}

// ---------------- counting sort by dst ----------------------------------
__global__ void hist_kernel(const int* __restrict__ ei, int* __restrict__ cnt) {
    int e = blockIdx.x * 256 + threadIdx.x;   // grid 6250 x 256 == NE
    atomicAdd(&cnt[ei[NE + e]], 1);
}

__global__ void scan_block_kernel(const int* __restrict__ cnt,
                                  int* __restrict__ offs,
                                  int* __restrict__ bsums) {
    __shared__ int tmp[256];
    int b = blockIdx.x, i = threadIdx.x, idx = b * 256 + i;
    int v = (idx < NN) ? cnt[idx] : 0;
    tmp[i] = v;
    __syncthreads();
    #pragma unroll
    for (int off = 1; off < 256; off <<= 1) {
        int t2 = (i >= off) ? tmp[i - off] : 0;
        __syncthreads();
        tmp[i] += t2;
        __syncthreads();
    }
    if (idx < NN) offs[idx] = tmp[i] - v;   // exclusive
    if (i == 255) bsums[b] = tmp[255];
}

__global__ void scan_sums_kernel(int* __restrict__ bsums) {
    __shared__ int tmp[512];
    int i = threadIdx.x;
    int v = (i < NB1) ? bsums[i] : 0;
    tmp[i] = v;
    __syncthreads();
    #pragma unroll
    for (int off = 1; off < 512; off <<= 1) {
        int t2 = (i >= off) ? tmp[i - off] : 0;
        __syncthreads();
        tmp[i] += t2;
        __syncthreads();
    }
    if (i < NB1) bsums[i] = tmp[i] - v;     // exclusive
}

__global__ void scan_add_kernel(int* __restrict__ offs,
                                const int* __restrict__ bsums,
                                int* __restrict__ cursor) {
    int b = blockIdx.x, idx = b * 256 + threadIdx.x;
    if (idx < NN) {
        int o = offs[idx] + bsums[b];
        offs[idx] = o;
        cursor[idx] = o;
    }
}

template <int USE_EA>
__global__ void scatter_kernel(const int* __restrict__ ei,
                               const float* __restrict__ ea,
                               int* __restrict__ cursor,
                               int2* __restrict__ sSD,
                               int* __restrict__ sE,
                               unsigned short* __restrict__ sEA) {
    int e = blockIdx.x * 256 + threadIdx.x;   // grid 6250 x 256 == NE
    int src = ei[e], dst = ei[NE + e];
    int pos = atomicAdd(&cursor[dst], 1);
    int2 sd; sd.x = src; sd.y = dst;
    sSD[pos] = sd;
    if (USE_EA) {
        const float4* eav = (const float4*)(ea + (size_t)e * ED);
        unsigned short tmp[16];
        #pragma unroll
        for (int j = 0; j < 4; j++) {
            float4 v = eav[j];
            tmp[j * 4 + 0] = f2bf(v.x); tmp[j * 4 + 1] = f2bf(v.y);
            tmp[j * 4 + 2] = f2bf(v.z); tmp[j * 4 + 3] = f2bf(v.w);
        }
        uint4* dp = (uint4*)(sEA + (size_t)pos * ED);
        dp[0] = ((const uint4*)tmp)[0];
        dp[1] = ((const uint4*)tmp)[1];
    } else {
        sE[pos] = e;
    }
}

// ---------------- edge MLP on dst-sorted edges + segment-reduce ---------
template <int USE_EA>
__global__ __launch_bounds__(256, 3) void edge_sorted_kernel(
    const unsigned short* __restrict__ xb,
    const int2* __restrict__ sSD,
    const int* __restrict__ sE,
    const unsigned short* __restrict__ sEA,
    const float* __restrict__ ea,
    const unsigned short* __restrict__ W1T,
    const unsigned short* __restrict__ W2T,
    const float* __restrict__ b1,
    const float* __restrict__ b2,
    float* __restrict__ agg) {
    __shared__ unsigned short sW1[64 * K1S];                   // 21504 B
    __shared__ __align__(16) char sAU[64 * K1S * 2];            // 21504 B: sA (bf16) / sM (fp32 64 x MS)
    __shared__ unsigned short sH[64 * K2S];                     // 9216 B
    __shared__ int sDst[64];
    unsigned short* sA = (unsigned short*)sAU;
    float* sM = (float*)sAU;

    int t = threadIdx.x;
    int lane = t & 63, w = t >> 6;
    int m = lane & 15, q = lane >> 4;

    // W2 B-fragments straight to registers (9 KB, hot in L2)
    short8 w2f[2][4];
    #pragma unroll
    for (int kt = 0; kt < 2; kt++)
        #pragma unroll
        for (int tt = 0; tt < 4; tt++)
            w2f[kt][tt] = *(const short8*)(W2T + (tt * 16 + m) * K2S + kt * 32 + q * 8);

    // stage W1 (pre-packed, contiguous)
    {
        const uint4* wv = (const uint4*)W1T;
        uint4* sv = (uint4*)sW1;
        for (int i = t; i < 64 * K1S * 2 / 16; i += 256) sv[i] = wv[i];
    }

    // gather A tile: 4 threads per sorted edge
    {
        int eL = t >> 2, sub = t & 3;
        int gi = blockIdx.x * 64 + eL;
        int2 sd = sSD[gi];
        if (sub == 0) sDst[eL] = sd.y;
        const uint4* xs = (const uint4*)(xb + (size_t)sd.x * H);
        const uint4* xd = (const uint4*)(xb + (size_t)sd.y * H);
        uint4* arow = (uint4*)(sA + eL * K1S);
        arow[sub * 2]     = xs[sub * 2];
        arow[sub * 2 + 1] = xs[sub * 2 + 1];
        arow[8 + sub * 2]     = xd[sub * 2];
        arow[8 + sub * 2 + 1] = xd[sub * 2 + 1];
        if (USE_EA) {
            const uint2* eav = (const uint2*)(sEA + (size_t)gi * ED);
            *(uint2*)(sA + eL * K1S + 128 + sub * 4) = eav[sub];
        } else {
            int e2 = sE[gi];
            const float4* eav = (const float4*)(ea + (size_t)e2 * ED);
            float4 v = eav[sub];
            unsigned short* er = sA + eL * K1S + 128 + sub * 4;
            er[0] = f2bf(v.x); er[1] = f2bf(v.y);
            er[2] = f2bf(v.z); er[3] = f2bf(v.w);
        }
        unsigned short* zp = sA + eL * K1S + 144 + sub * 4;
        zp[0] = 0; zp[1] = 0; zp[2] = 0; zp[3] = 0;
    }
    __syncthreads();

    // GEMM1: [16 x 160] @ [160 x 64]
    floatx4 acc[4];
    #pragma unroll
    for (int i = 0; i < 4; i++) acc[i] = (floatx4){0.f, 0.f, 0.f, 0.f};
    int arowi = w * 16 + m;
    #pragma unroll
    for (int kt = 0; kt < 5; kt++) {
        short8 a = *(const short8*)(sA + arowi * K1S + kt * 32 + q * 8);
        #pragma unroll
        for (int tt = 0; tt < 4; tt++) {
            short8 b = *(const short8*)(sW1 + (tt * 16 + m) * K1S + kt * 32 + q * 8);
            acc[tt] = __builtin_amdgcn_mfma_f32_16x16x32_bf16(a, b, acc[tt], 0, 0, 0);
        }
    }

    // epilogue 1: bias + SiLU -> sH (A-layout for GEMM2)
    #pragma unroll
    for (int tt = 0; tt < 4; tt++) {
        int c = tt * 16 + m;
        float bias = b1[c];
        #pragma unroll
        for (int r = 0; r < 4; r++) {
            float hv = silu(acc[tt][r] + bias);
            sH[(w * 16 + q * 4 + r) * K2S + c] = f2bf(hv);
        }
    }
    __syncthreads();   // all GEMM1 sA reads done; sH visible

    // GEMM2: [16 x 64] @ [64 x 64] (B from registers)
    floatx4 acc2[4];
    #pragma unroll
    for (int i = 0; i < 4; i++) acc2[i] = (floatx4){0.f, 0.f, 0.f, 0.f};
    #pragma unroll
    for (int kt = 0; kt < 2; kt++) {
        short8 a = *(const short8*)(sH + arowi * K2S + kt * 32 + q * 8);
        #pragma unroll
        for (int tt = 0; tt < 4; tt++) {
            acc2[tt] = __builtin_amdgcn_mfma_f32_16x16x32_bf16(a, w2f[kt][tt], acc2[tt], 0, 0, 0);
        }
    }

    // epilogue 2: bias + SiLU -> sM (fp32, aliases sA — safe after barrier)
    #pragma unroll
    for (int tt = 0; tt < 4; tt++) {
        int c = tt * 16 + m;
        float bias = b2[c];
        #pragma unroll
        for (int r = 0; r < 4; r++) {
            sM[(w * 16 + q * 4 + r) * MS + c] = silu(acc2[tt][r] + bias);
        }
    }
    __syncthreads();   // make sM writes visible across lanes (and defeat TBAA reordering)

    // segment-reduce: wave w reduces rows [w*16, w*16+16), lane = column.
    // dst is nondecreasing (counting sort) -> runs; branch is wave-uniform.
    {
        int c = lane;
        float s = 0.f;
        int cur = sDst[w * 16];
        #pragma unroll
        for (int r = 0; r < 16; r++) {
            int rr = w * 16 + r;
            int d = sDst[rr];
            if (d != cur) {
                atomicAdd(&agg[(size_t)cur * H + c], s);
                s = 0.f;
                cur = d;
            }
            s += sM[rr * MS + c];
        }
        atomicAdd(&agg[(size_t)cur * H + c], s);
    }
}

// ---------------- node MLP ----------------------------------------------
__global__ __launch_bounds__(256) void node_kernel(
    const unsigned short* __restrict__ xb,
    const float* __restrict__ agg,
    const unsigned short* __restrict__ W3T,
    const float* __restrict__ b3,
    float* __restrict__ out) {
    __shared__ unsigned short sW3[64 * K3S];
    __shared__ unsigned short sA[64 * K3S];

    int t = threadIdx.x;
    int n0 = blockIdx.x * 64;

    {
        const uint4* wv = (const uint4*)W3T;
        uint4* sv = (uint4*)sW3;
        for (int i = t; i < 64 * K3S * 2 / 16; i += 256) sv[i] = wv[i];
    }

    {
        int nL = t >> 2, sub = t & 3;
        int node = n0 + nL;
        uint4* arow = (uint4*)(sA + nL * K3S);
        if (node < NN) {
            const uint4* xs = (const uint4*)(xb + (size_t)node * H);
            arow[sub * 2]     = xs[sub * 2];
            arow[sub * 2 + 1] = xs[sub * 2 + 1];
            const float4* av = (const float4*)(agg + (size_t)node * H);
            unsigned short tmp[16];
            #pragma unroll
            for (int j = 0; j < 4; j++) {
                float4 v = av[sub * 4 + j];
                tmp[j * 4 + 0] = f2bf(v.x); tmp[j * 4 + 1] = f2bf(v.y);
                tmp[j * 4 + 2] = f2bf(v.z); tmp[j * 4 + 3] = f2bf(v.w);
            }
            uint4* drow = (uint4*)(sA + nL * K3S + 64 + sub * 16);
            drow[0] = ((const uint4*)tmp)[0];
            drow[1] = ((const uint4*)tmp)[1];
        } else {
            uint4 z = {0, 0, 0, 0};
            arow[sub * 2] = z; arow[sub * 2 + 1] = z;
            uint4* drow = (uint4*)(sA + nL * K3S + 64 + sub * 16);
            drow[0] = z; drow[1] = z;
        }
    }
    __syncthreads();

    int w = t >> 6;
    int lane = t & 63;
    int m = lane & 15;
    int q = lane >> 4;

    floatx4 acc[4];
    #pragma unroll
    for (int i = 0; i < 4; i++) acc[i] = (floatx4){0.f, 0.f, 0.f, 0.f};
    int arowi = w * 16 + m;
    #pragma unroll
    for (int kt = 0; kt < 4; kt++) {
        short8 a = *(const short8*)(sA + arowi * K3S + kt * 32 + q * 8);
        #pragma unroll
        for (int tt = 0; tt < 4; tt++) {
            short8 b = *(const short8*)(sW3 + (tt * 16 + m) * K3S + kt * 32 + q * 8);
            acc[tt] = __builtin_amdgcn_mfma_f32_16x16x32_bf16(a, b, acc[tt], 0, 0, 0);
        }
    }

    #pragma unroll
    for (int tt = 0; tt < 4; tt++) {
        int c = tt * 16 + m;
        float bias = b3[c];
        #pragma unroll
        for (int r = 0; r < 4; r++) {
            int row = w * 16 + q * 4 + r;
            int node = n0 + row;
            if (node < NN) {
                out[(size_t)node * H + c] = silu(acc[tt][r] + bias);
            }
        }
    }
}

static inline size_t align256(size_t x) { return (x + 255) & ~(size_t)255; }

extern "C" void kernel_launch(void* const* d_in, const int* in_sizes, int n_in,
                              void* d_out, int out_size, void* d_ws, size_t ws_size,
                              hipStream_t stream) {
    const float* x  = (const float*)d_in[0];
    const int*   ei = (const int*)d_in[1];
    const float* ea = (const float*)d_in[2];
    const float* W1 = (const float*)d_in[3];
    const float* b1 = (const float*)d_in[4];
    const float* W2 = (const float*)d_in[5];
    const float* b2 = (const float*)d_in[6];
    const float* W3 = (const float*)d_in[7];
    const float* b3 = (const float*)d_in[8];
    float* out = (float*)d_out;

    char* ws = (char*)d_ws;
    size_t o = 0;
    float* agg = (float*)(ws + o);           o = align256(o + (size_t)NN * H * 4);
    unsigned short* xb = (unsigned short*)(ws + o);  o = align256(o + (size_t)NN * H * 2);
    unsigned short* W1T = (unsigned short*)(ws + o); o = align256(o + 64 * K1S * 2);
    unsigned short* W2T = (unsigned short*)(ws + o); o = align256(o + 64 * K2S * 2);
    unsigned short* W3T = (unsigned short*)(ws + o); o = align256(o + 64 * K3S * 2);
    int* offs = (int*)(ws + o);              o = align256(o + (size_t)NN * 4);
    int* bsums = (int*)(ws + o);             o = align256(o + NB1 * 4);
    int* cnt = (int*)(ws + o);               o = align256(o + (size_t)NN * 4);  // reused as cursor
    int2* sSD = (int2*)(ws + o);             o = align256(o + (size_t)NE * 8);
    int* sE = (int*)(ws + o);                o = align256(o + (size_t)NE * 4);
    unsigned short* sEA = (unsigned short*)(ws + o);
    size_t needEA = o + (size_t)NE * ED * 2;
    bool useEA = (ws_size >= needEA);

    int* cursor = cnt;

    hipMemsetAsync(agg, 0, (size_t)NN * H * sizeof(float), stream);
    hipMemsetAsync(cnt, 0, (size_t)NN * sizeof(int), stream);
    prep_kernel<<<2048, 256, 0, stream>>>(x, W1, W2, W3, xb, W1T, W2T, W3T);
    hist_kernel<<<NE / 256, 256, 0, stream>>>(ei, cnt);
    scan_block_kernel<<<NB1, 256, 0, stream>>>(cnt, offs, bsums);
    scan_sums_kernel<<<1, 512, 0, stream>>>(bsums);
    scan_add_kernel<<<NB1, 256, 0, stream>>>(offs, bsums, cursor);
    if (useEA) {
        scatter_kernel<1><<<NE / 256, 256, 0, stream>>>(ei, ea, cursor, sSD, sE, sEA);
        edge_sorted_kernel<1><<<NT, 256, 0, stream>>>(xb, sSD, sE, sEA, ea, W1T, W2T, b1, b2, agg);
    } else {
        scatter_kernel<0><<<NE / 256, 256, 0, stream>>>(ei, ea, cursor, sSD, sE, sEA);
        edge_sorted_kernel<0><<<NT, 256, 0, stream>>>(xb, sSD, sE, sEA, ea, W1T, W2T, b1, b2, agg);
    }
    node_kernel<<<(NN + 63) / 64, 256, 0, stream>>>(xb, agg, W3T, b3, out);
}

// Round 3
// 558.007 us; speedup vs baseline: 1.1209x; 1.0233x over previous
//
#include <hip/hip_runtime.h>
#include <hip/hip_bf16.h>

#define NE 1600000
#define NN 100000
#define H 64
#define ED 16
#define NT (NE / 64)        // 25000 edge tiles
#define NB1 391             // ceil(NN/256) scan blocks
#define NNB 1563            // ceil(NN/64) node tiles

#define KS  72    // bf16 K-stride for K=64 packs (W1ab, W2, sH)
#define K3S 136   // bf16 row stride, node GEMM (K=128)
#define YS  68    // fp32 row stride for ysum / message buffer

typedef __attribute__((ext_vector_type(8))) short short8;
typedef __attribute__((ext_vector_type(4))) float floatx4;

__device__ __forceinline__ unsigned short f2bf(float f) {
    union { float f; unsigned u; } v; v.f = f;
    unsigned r = v.u + 0x7fff + ((v.u >> 16) & 1);
    return (unsigned short)(r >> 16);
}

__device__ __forceinline__ float bf2f(unsigned short u) {
    union { unsigned u; float f; } v; v.u = ((unsigned)u) << 16;
    return v.f;
}

__device__ __forceinline__ float silu(float x) {
    return x / (1.0f + __expf(-x));
}

// ---- prep: x->bf16, weight packs, histogram (fused) --------------------
__global__ void prep_kernel(const float* __restrict__ x,
                            const float* __restrict__ W1,
                            const float* __restrict__ b1,
                            const float* __restrict__ W2,
                            const float* __restrict__ W3,
                            const int* __restrict__ ei,
                            unsigned short* __restrict__ xb,
                            unsigned short* __restrict__ W1abT,
                            unsigned short* __restrict__ W1cT,
                            unsigned short* __restrict__ W2T,
                            unsigned short* __restrict__ W3T,
                            int* __restrict__ cnt) {
    int tid = blockIdx.x * blockDim.x + threadIdx.x;
    int nt = gridDim.x * blockDim.x;
    const float4* xv = (const float4*)x;
    ushort4* xbv = (ushort4*)xb;
    for (int i = tid; i < NN * H / 4; i += nt) {
        float4 v = xv[i];
        ushort4 o;
        o.x = f2bf(v.x); o.y = f2bf(v.y); o.z = f2bf(v.z); o.w = f2bf(v.w);
        xbv[i] = o;
    }
    // W1abT[n][k]: n<64 -> W1[k][n] (x_src part); n in 64..127 -> W1[64+k][n-64]
    for (int i = tid; i < 128 * KS; i += nt) {
        int n = i / KS, k = i % KS;
        W1abT[i] = (k < 64) ? f2bf(W1[(size_t)((n < 64) ? k : 64 + k) * 64 + (n & 63)])
                            : (unsigned short)0;
    }
    // W1cT[n][k]: k<16 -> W1[128+k][n]; k==16 -> b1[n] (bias slot); else 0
    for (int i = tid; i < 64 * 32; i += nt) {
        int n = i / 32, k = i % 32;
        unsigned short v = 0;
        if (k < 16) v = f2bf(W1[(size_t)(128 + k) * 64 + n]);
        else if (k == 16) v = f2bf(b1[n]);
        W1cT[i] = v;
    }
    for (int i = tid; i < 64 * KS; i += nt) {
        int n = i / KS, k = i % KS;
        W2T[i] = (k < 64) ? f2bf(W2[k * 64 + n]) : (unsigned short)0;
    }
    for (int i = tid; i < 64 * K3S; i += nt) {
        int n = i / K3S, k = i % K3S;
        W3T[i] = (k < 128) ? f2bf(W3[k * 64 + n]) : (unsigned short)0;
    }
    // histogram of dst
    for (int e = tid; e < NE; e += nt) {
        atomicAdd(&cnt[ei[NE + e]], 1);
    }
}

// ---- counting-sort scan ------------------------------------------------
__global__ void scan_block_kernel(const int* __restrict__ cnt,
                                  int* __restrict__ offs,
                                  int* __restrict__ bsums) {
    __shared__ int tmp[256];
    int b = blockIdx.x, i = threadIdx.x, idx = b * 256 + i;
    int v = (idx < NN) ? cnt[idx] : 0;
    tmp[i] = v;
    __syncthreads();
    #pragma unroll
    for (int off = 1; off < 256; off <<= 1) {
        int t2 = (i >= off) ? tmp[i - off] : 0;
        __syncthreads();
        tmp[i] += t2;
        __syncthreads();
    }
    if (idx < NN) offs[idx] = tmp[i] - v;
    if (i == 255) bsums[b] = tmp[255];
}

__global__ void scan_sums_kernel(int* __restrict__ bsums) {
    __shared__ int tmp[512];
    int i = threadIdx.x;
    int v = (i < NB1) ? bsums[i] : 0;
    tmp[i] = v;
    __syncthreads();
    #pragma unroll
    for (int off = 1; off < 512; off <<= 1) {
        int t2 = (i >= off) ? tmp[i - off] : 0;
        __syncthreads();
        tmp[i] += t2;
        __syncthreads();
    }
    if (i < NB1) bsums[i] = tmp[i] - v;
}

__global__ void scan_add_kernel(int* __restrict__ offs,
                                const int* __restrict__ bsums,
                                int* __restrict__ cursor) {
    int b = blockIdx.x, idx = b * 256 + threadIdx.x;
    if (idx < NN) {
        int o = offs[idx] + bsums[b];
        offs[idx] = o;
        cursor[idx] = o;
    }
}

__global__ void scatter_kernel(const int* __restrict__ ei,
                               int* __restrict__ cursor,
                               int4* __restrict__ sSDE) {
    int e = blockIdx.x * 256 + threadIdx.x;   // grid 6250 x 256 == NE
    int src = ei[e], dst = ei[NE + e];
    int pos = atomicAdd(&cursor[dst], 1);
    int4 v; v.x = src; v.y = dst; v.z = e; v.w = 0;
    sSDE[pos] = v;
}

// ---- y12: yc[node] = [x@W1a | x@W1b] in bf16 ---------------------------
__global__ __launch_bounds__(256) void y12_kernel(
    const unsigned short* __restrict__ xb,
    const unsigned short* __restrict__ W1abT,
    unsigned short* __restrict__ yc) {
    __shared__ unsigned short sW[128 * KS];   // 18432 B
    int t = threadIdx.x;
    {
        const uint4* wv = (const uint4*)W1abT;
        uint4* sv = (uint4*)sW;
        for (int i = t; i < 128 * KS * 2 / 16; i += 256) sv[i] = wv[i];
    }
    __syncthreads();

    int lane = t & 63, w = t >> 6;
    int m = lane & 15, q = lane >> 4;
    int n0 = blockIdx.x * 64;
    int anode = n0 + w * 16 + m;
    int aclamp = (anode < NN) ? anode : (NN - 1);

    floatx4 acc[8];
    #pragma unroll
    for (int i = 0; i < 8; i++) acc[i] = (floatx4){0.f, 0.f, 0.f, 0.f};
    #pragma unroll
    for (int kt = 0; kt < 2; kt++) {
        short8 a = *(const short8*)(xb + (size_t)aclamp * H + kt * 32 + q * 8);
        #pragma unroll
        for (int tt = 0; tt < 8; tt++) {
            short8 b = *(const short8*)(sW + (tt * 16 + m) * KS + kt * 32 + q * 8);
            acc[tt] = __builtin_amdgcn_mfma_f32_16x16x32_bf16(a, b, acc[tt], 0, 0, 0);
        }
    }
    #pragma unroll
    for (int tt = 0; tt < 8; tt++) {
        int c = tt * 16 + m;
        #pragma unroll
        for (int r = 0; r < 4; r++) {
            int node = n0 + w * 16 + q * 4 + r;
            if (node < NN) yc[(size_t)node * 128 + c] = f2bf(acc[tt][r]);
        }
    }
}

// ---- edge: h = silu(y1[src]+y2[dst]+ea@W1c+b1); m = silu(h@W2+b2); agg --
__global__ __launch_bounds__(256, 4) void edge_kernel(
    const unsigned short* __restrict__ yc,
    const float* __restrict__ ea,
    const int4* __restrict__ sSDE,
    const unsigned short* __restrict__ W1cT,
    const unsigned short* __restrict__ W2T,
    const float* __restrict__ b2,
    float* __restrict__ agg) {
    __shared__ float sY[64 * YS];            // 17408 B (aliased as sM later)
    __shared__ unsigned short sH[64 * KS];   // 9216 B
    __shared__ int sDst[64];
    __shared__ int sEid[64];
    float* sM = sY;

    int t = threadIdx.x;
    int lane = t & 63, w = t >> 6;
    int m = lane & 15, q = lane >> 4;

    // B fragments from global (4KB + 9KB, L2-hot across all blocks)
    short8 w1c[4], w2f[2][4];
    #pragma unroll
    for (int tt = 0; tt < 4; tt++)
        w1c[tt] = *(const short8*)(W1cT + (tt * 16 + m) * 32 + q * 8);
    #pragma unroll
    for (int kt = 0; kt < 2; kt++)
        #pragma unroll
        for (int tt = 0; tt < 4; tt++)
            w2f[kt][tt] = *(const short8*)(W2T + (tt * 16 + m) * KS + kt * 32 + q * 8);

    // stage ysum = y1[src] + y2[dst] (fp32) — 4 threads per edge
    {
        int eL = t >> 2, sub = t & 3;
        int gi = blockIdx.x * 64 + eL;
        int4 sde = sSDE[gi];
        if (sub == 0) { sDst[eL] = sde.y; sEid[eL] = sde.z; }
        const unsigned short* ys = yc + (size_t)sde.x * 128 + sub * 16;
        const unsigned short* yd = yc + (size_t)sde.y * 128 + 64 + sub * 16;
        short8 a0 = *(const short8*)(ys);
        short8 a1 = *(const short8*)(ys + 8);
        short8 d0 = *(const short8*)(yd);
        short8 d1 = *(const short8*)(yd + 8);
        float* o = sY + eL * YS + sub * 16;
        #pragma unroll
        for (int j = 0; j < 8; j++) {
            o[j]     = bf2f((unsigned short)a0[j]) + bf2f((unsigned short)d0[j]);
            o[8 + j] = bf2f((unsigned short)a1[j]) + bf2f((unsigned short)d1[j]);
        }
    }
    __syncthreads();

    // GEMM1 (K=32): ea@W1c with b1 folded at k=16 via 1.0 input
    int e = sEid[w * 16 + m];
    short8 af = {0, 0, 0, 0, 0, 0, 0, 0};
    if (q < 2) {
        const float4* p = (const float4*)(ea + (size_t)e * ED + q * 8);
        float4 v0 = p[0], v1 = p[1];
        af[0] = (short)f2bf(v0.x); af[1] = (short)f2bf(v0.y);
        af[2] = (short)f2bf(v0.z); af[3] = (short)f2bf(v0.w);
        af[4] = (short)f2bf(v1.x); af[5] = (short)f2bf(v1.y);
        af[6] = (short)f2bf(v1.z); af[7] = (short)f2bf(v1.w);
    } else if (q == 2) {
        af[0] = (short)0x3F80;   // bf16 1.0 -> multiplies b1 row (k=16)
    }
    floatx4 acc[4];
    #pragma unroll
    for (int i = 0; i < 4; i++) acc[i] = (floatx4){0.f, 0.f, 0.f, 0.f};
    #pragma unroll
    for (int tt = 0; tt < 4; tt++)
        acc[tt] = __builtin_amdgcn_mfma_f32_16x16x32_bf16(af, w1c[tt], acc[tt], 0, 0, 0);

    // epilogue 1: h = silu(acc + ysum) -> sH (A-layout for GEMM2)
    #pragma unroll
    for (int tt = 0; tt < 4; tt++) {
        int c = tt * 16 + m;
        #pragma unroll
        for (int r = 0; r < 4; r++) {
            int row = w * 16 + q * 4 + r;
            float hv = silu(acc[tt][r] + sY[row * YS + c]);
            sH[row * KS + c] = f2bf(hv);
        }
    }
    __syncthreads();   // sH visible; all sY reads complete (sM aliasing safe)

    // GEMM2: [16x64]@[64x64], B in registers
    int arowi = w * 16 + m;
    floatx4 acc2[4];
    #pragma unroll
    for (int i = 0; i < 4; i++) acc2[i] = (floatx4){0.f, 0.f, 0.f, 0.f};
    #pragma unroll
    for (int kt = 0; kt < 2; kt++) {
        short8 a = *(const short8*)(sH + arowi * KS + kt * 32 + q * 8);
        #pragma unroll
        for (int tt = 0; tt < 4; tt++)
            acc2[tt] = __builtin_amdgcn_mfma_f32_16x16x32_bf16(a, w2f[kt][tt], acc2[tt], 0, 0, 0);
    }

    // epilogue 2: messages -> sM (fp32, aliases sY)
    #pragma unroll
    for (int tt = 0; tt < 4; tt++) {
        int c = tt * 16 + m;
        float bias = b2[c];
        #pragma unroll
        for (int r = 0; r < 4; r++) {
            sM[(w * 16 + q * 4 + r) * YS + c] = silu(acc2[tt][r] + bias);
        }
    }
    __syncthreads();

    // segment-reduce: wave w reduces rows [w*16, w*16+16), lane = column
    {
        int c = lane;
        float s = 0.f;
        int cur = sDst[w * 16];
        #pragma unroll
        for (int r = 0; r < 16; r++) {
            int rr = w * 16 + r;
            int d = sDst[rr];
            if (d != cur) {
                atomicAdd(&agg[(size_t)cur * H + c], s);
                s = 0.f;
                cur = d;
            }
            s += sM[rr * YS + c];
        }
        atomicAdd(&agg[(size_t)cur * H + c], s);
    }
}

// ---- node MLP ----------------------------------------------------------
__global__ __launch_bounds__(256) void node_kernel(
    const unsigned short* __restrict__ xb,
    const float* __restrict__ agg,
    const unsigned short* __restrict__ W3T,
    const float* __restrict__ b3,
    float* __restrict__ out) {
    __shared__ unsigned short sW3[64 * K3S];
    __shared__ unsigned short sA[64 * K3S];

    int t = threadIdx.x;
    int n0 = blockIdx.x * 64;

    {
        const uint4* wv = (const uint4*)W3T;
        uint4* sv = (uint4*)sW3;
        for (int i = t; i < 64 * K3S * 2 / 16; i += 256) sv[i] = wv[i];
    }
    {
        int nL = t >> 2, sub = t & 3;
        int node = n0 + nL;
        uint4* arow = (uint4*)(sA + nL * K3S);
        if (node < NN) {
            const uint4* xs = (const uint4*)(xb + (size_t)node * H);
            arow[sub * 2]     = xs[sub * 2];
            arow[sub * 2 + 1] = xs[sub * 2 + 1];
            const float4* av = (const float4*)(agg + (size_t)node * H);
            unsigned short tmp[16];
            #pragma unroll
            for (int j = 0; j < 4; j++) {
                float4 v = av[sub * 4 + j];
                tmp[j * 4 + 0] = f2bf(v.x); tmp[j * 4 + 1] = f2bf(v.y);
                tmp[j * 4 + 2] = f2bf(v.z); tmp[j * 4 + 3] = f2bf(v.w);
            }
            uint4* drow = (uint4*)(sA + nL * K3S + 64 + sub * 16);
            drow[0] = ((const uint4*)tmp)[0];
            drow[1] = ((const uint4*)tmp)[1];
        } else {
            uint4 z = {0, 0, 0, 0};
            arow[sub * 2] = z; arow[sub * 2 + 1] = z;
            uint4* drow = (uint4*)(sA + nL * K3S + 64 + sub * 16);
            drow[0] = z; drow[1] = z;
        }
    }
    __syncthreads();

    int w = t >> 6, lane = t & 63;
    int m = lane & 15, q = lane >> 4;

    floatx4 acc[4];
    #pragma unroll
    for (int i = 0; i < 4; i++) acc[i] = (floatx4){0.f, 0.f, 0.f, 0.f};
    int arowi = w * 16 + m;
    #pragma unroll
    for (int kt = 0; kt < 4; kt++) {
        short8 a = *(const short8*)(sA + arowi * K3S + kt * 32 + q * 8);
        #pragma unroll
        for (int tt = 0; tt < 4; tt++) {
            short8 b = *(const short8*)(sW3 + (tt * 16 + m) * K3S + kt * 32 + q * 8);
            acc[tt] = __builtin_amdgcn_mfma_f32_16x16x32_bf16(a, b, acc[tt], 0, 0, 0);
        }
    }
    #pragma unroll
    for (int tt = 0; tt < 4; tt++) {
        int c = tt * 16 + m;
        float bias = b3[c];
        #pragma unroll
        for (int r = 0; r < 4; r++) {
            int node = n0 + w * 16 + q * 4 + r;
            if (node < NN) out[(size_t)node * H + c] = silu(acc[tt][r] + bias);
        }
    }
}

static inline size_t align256(size_t x) { return (x + 255) & ~(size_t)255; }

extern "C" void kernel_launch(void* const* d_in, const int* in_sizes, int n_in,
                              void* d_out, int out_size, void* d_ws, size_t ws_size,
                              hipStream_t stream) {
    const float* x  = (const float*)d_in[0];
    const int*   ei = (const int*)d_in[1];
    const float* ea = (const float*)d_in[2];
    const float* W1 = (const float*)d_in[3];
    const float* b1 = (const float*)d_in[4];
    const float* W2 = (const float*)d_in[5];
    const float* b2 = (const float*)d_in[6];
    const float* W3 = (const float*)d_in[7];
    const float* b3 = (const float*)d_in[8];
    float* out = (float*)d_out;

    char* ws = (char*)d_ws;
    size_t o = 0;
    float* agg = (float*)(ws + o);                    o = align256(o + (size_t)NN * H * 4);
    unsigned short* xb = (unsigned short*)(ws + o);   o = align256(o + (size_t)NN * H * 2);
    unsigned short* yc = (unsigned short*)(ws + o);   o = align256(o + (size_t)NN * 128 * 2);
    unsigned short* W1abT = (unsigned short*)(ws + o); o = align256(o + 128 * KS * 2);
    unsigned short* W1cT = (unsigned short*)(ws + o); o = align256(o + 64 * 32 * 2);
    unsigned short* W2T = (unsigned short*)(ws + o);  o = align256(o + 64 * KS * 2);
    unsigned short* W3T = (unsigned short*)(ws + o);  o = align256(o + 64 * K3S * 2);
    int* offs = (int*)(ws + o);                       o = align256(o + (size_t)NN * 4);
    int* bsums = (int*)(ws + o);                      o = align256(o + NB1 * 4);
    int* cnt = (int*)(ws + o);                        o = align256(o + (size_t)NN * 4);
    int4* sSDE = (int4*)(ws + o);                     o = align256(o + (size_t)NE * 16);

    int* cursor = cnt;

    hipMemsetAsync(agg, 0, (size_t)NN * H * sizeof(float), stream);
    hipMemsetAsync(cnt, 0, (size_t)NN * sizeof(int), stream);
    prep_kernel<<<2048, 256, 0, stream>>>(x, W1, b1, W2, W3, ei, xb, W1abT, W1cT, W2T, W3T, cnt);
    scan_block_kernel<<<NB1, 256, 0, stream>>>(cnt, offs, bsums);
    scan_sums_kernel<<<1, 512, 0, stream>>>(bsums);
    scan_add_kernel<<<NB1, 256, 0, stream>>>(offs, bsums, cursor);
    scatter_kernel<<<NE / 256, 256, 0, stream>>>(ei, cursor, sSDE);
    y12_kernel<<<NNB, 256, 0, stream>>>(xb, W1abT, yc);
    edge_kernel<<<NT, 256, 0, stream>>>(yc, ea, sSDE, W1cT, W2T, b2, agg);
    node_kernel<<<NNB, 256, 0, stream>>>(xb, agg, W3T, b3, out);
}

// Round 4
// 546.357 us; speedup vs baseline: 1.1448x; 1.0213x over previous
//
#include <hip/hip_runtime.h>
#include <hip/hip_bf16.h>

#define NE 1600000
#define NN 100000
#define H 64
#define ED 16
#define NT (NE / 64)        // 25000 edge tiles
#define NB1 391             // ceil(NN/256) scan blocks
#define NNB 1563            // ceil(NN/64) node tiles

#define KS  72    // bf16 K-stride for K=64 packs (W1ab, W2, sH)
#define K3S 136   // bf16 row stride, node GEMM (K=128)
#define YS  68    // fp32 row stride for ysum / message buffer

typedef __attribute__((ext_vector_type(8))) short short8;
typedef __attribute__((ext_vector_type(4))) float floatx4;

__device__ __forceinline__ unsigned short f2bf(float f) {
    union { float f; unsigned u; } v; v.f = f;
    unsigned r = v.u + 0x7fff + ((v.u >> 16) & 1);
    return (unsigned short)(r >> 16);
}

__device__ __forceinline__ float bf2f(unsigned short u) {
    union { unsigned u; float f; } v; v.u = ((unsigned)u) << 16;
    return v.f;
}

__device__ __forceinline__ float silu(float x) {
    return x / (1.0f + __expf(-x));
}

// ---- prep: x->bf16, weight packs, histogram (fused) --------------------
__global__ void prep_kernel(const float* __restrict__ x,
                            const float* __restrict__ W1,
                            const float* __restrict__ b1,
                            const float* __restrict__ W2,
                            const float* __restrict__ W3,
                            const int* __restrict__ ei,
                            unsigned short* __restrict__ xb,
                            unsigned short* __restrict__ W1abT,
                            unsigned short* __restrict__ W1cT,
                            unsigned short* __restrict__ W2T,
                            unsigned short* __restrict__ W3T,
                            int* __restrict__ cnt) {
    int tid = blockIdx.x * blockDim.x + threadIdx.x;
    int nt = gridDim.x * blockDim.x;
    const float4* xv = (const float4*)x;
    ushort4* xbv = (ushort4*)xb;
    for (int i = tid; i < NN * H / 4; i += nt) {
        float4 v = xv[i];
        ushort4 o;
        o.x = f2bf(v.x); o.y = f2bf(v.y); o.z = f2bf(v.z); o.w = f2bf(v.w);
        xbv[i] = o;
    }
    // W1abT[n][k]: n<64 -> W1[k][n] (x_src part); n in 64..127 -> W1[64+k][n-64]
    for (int i = tid; i < 128 * KS; i += nt) {
        int n = i / KS, k = i % KS;
        W1abT[i] = (k < 64) ? f2bf(W1[(size_t)((n < 64) ? k : 64 + k) * 64 + (n & 63)])
                            : (unsigned short)0;
    }
    // W1cT[n][k]: k<16 -> W1[128+k][n]; k==16 -> b1[n] (bias slot); else 0
    for (int i = tid; i < 64 * 32; i += nt) {
        int n = i / 32, k = i % 32;
        unsigned short v = 0;
        if (k < 16) v = f2bf(W1[(size_t)(128 + k) * 64 + n]);
        else if (k == 16) v = f2bf(b1[n]);
        W1cT[i] = v;
    }
    for (int i = tid; i < 64 * KS; i += nt) {
        int n = i / KS, k = i % KS;
        W2T[i] = (k < 64) ? f2bf(W2[k * 64 + n]) : (unsigned short)0;
    }
    for (int i = tid; i < 64 * K3S; i += nt) {
        int n = i / K3S, k = i % K3S;
        W3T[i] = (k < 128) ? f2bf(W3[k * 64 + n]) : (unsigned short)0;
    }
    // histogram of dst
    for (int e = tid; e < NE; e += nt) {
        atomicAdd(&cnt[ei[NE + e]], 1);
    }
}

// ---- counting-sort scan ------------------------------------------------
__global__ void scan_block_kernel(const int* __restrict__ cnt,
                                  int* __restrict__ offs,
                                  int* __restrict__ bsums) {
    __shared__ int tmp[256];
    int b = blockIdx.x, i = threadIdx.x, idx = b * 256 + i;
    int v = (idx < NN) ? cnt[idx] : 0;
    tmp[i] = v;
    __syncthreads();
    #pragma unroll
    for (int off = 1; off < 256; off <<= 1) {
        int t2 = (i >= off) ? tmp[i - off] : 0;
        __syncthreads();
        tmp[i] += t2;
        __syncthreads();
    }
    if (idx < NN) offs[idx] = tmp[i] - v;
    if (i == 255) bsums[b] = tmp[255];
}

__global__ void scan_sums_kernel(int* __restrict__ bsums) {
    __shared__ int tmp[512];
    int i = threadIdx.x;
    int v = (i < NB1) ? bsums[i] : 0;
    tmp[i] = v;
    __syncthreads();
    #pragma unroll
    for (int off = 1; off < 512; off <<= 1) {
        int t2 = (i >= off) ? tmp[i - off] : 0;
        __syncthreads();
        tmp[i] += t2;
        __syncthreads();
    }
    if (i < NB1) bsums[i] = tmp[i] - v;
}

__global__ void scan_add_kernel(int* __restrict__ offs,
                                const int* __restrict__ bsums,
                                int* __restrict__ cursor) {
    int b = blockIdx.x, idx = b * 256 + threadIdx.x;
    if (idx < NN) {
        int o = offs[idx] + bsums[b];
        offs[idx] = o;
        cursor[idx] = o;
    }
}

__global__ void scatter_kernel(const int* __restrict__ ei,
                               int* __restrict__ cursor,
                               int4* __restrict__ sSDE) {
    int e = blockIdx.x * 256 + threadIdx.x;   // grid 6250 x 256 == NE
    int src = ei[e], dst = ei[NE + e];
    int pos = atomicAdd(&cursor[dst], 1);
    int4 v; v.x = src; v.y = dst; v.z = e; v.w = 0;
    sSDE[pos] = v;
}

// ---- y12: yc[node] = [x@W1a | x@W1b] in bf16 (transposed MFMA) ---------
__global__ __launch_bounds__(256) void y12_kernel(
    const unsigned short* __restrict__ xb,
    const unsigned short* __restrict__ W1abT,
    unsigned short* __restrict__ yc) {
    __shared__ unsigned short sW[128 * KS];   // 18432 B
    int t = threadIdx.x;
    {
        const uint4* wv = (const uint4*)W1abT;
        uint4* sv = (uint4*)sW;
        for (int i = t; i < 128 * KS * 2 / 16; i += 256) sv[i] = wv[i];
    }
    __syncthreads();

    int lane = t & 63, w = t >> 6;
    int m = lane & 15, q = lane >> 4;
    int n0 = blockIdx.x * 64;
    int node = n0 + w * 16 + m;               // this lane's node (B-operand col)
    int nclamp = (node < NN) ? node : (NN - 1);

    floatx4 acc[8];
    #pragma unroll
    for (int i = 0; i < 8; i++) acc[i] = (floatx4){0.f, 0.f, 0.f, 0.f};
    #pragma unroll
    for (int kt = 0; kt < 2; kt++) {
        short8 bfr = *(const short8*)(xb + (size_t)nclamp * H + kt * 32 + q * 8);
        #pragma unroll
        for (int tt = 0; tt < 8; tt++) {
            short8 afr = *(const short8*)(sW + (tt * 16 + m) * KS + kt * 32 + q * 8);
            acc[tt] = __builtin_amdgcn_mfma_f32_16x16x32_bf16(afr, bfr, acc[tt], 0, 0, 0);
        }
    }
    // C' = y^T: lane holds node=node, channels tt*16+q*4+r (contiguous)
    if (node < NN) {
        #pragma unroll
        for (int tt = 0; tt < 8; tt++) {
            ushort4 o;
            o.x = f2bf(acc[tt][0]); o.y = f2bf(acc[tt][1]);
            o.z = f2bf(acc[tt][2]); o.w = f2bf(acc[tt][3]);
            *(ushort4*)(yc + (size_t)node * 128 + tt * 16 + q * 4) = o;
        }
    }
}

// ---- edge: h = silu(y1[src]+y2[dst]+ea@W1c+b1); m = silu(h@W2+b2); agg --
// All MFMAs transposed: weights as A, per-edge data as B -> lane owns one
// edge (col=m) and contiguous channels (rows) -> vector epilogues.
__global__ __launch_bounds__(256, 5) void edge_kernel(
    const unsigned short* __restrict__ yc,
    const float* __restrict__ ea,
    const int4* __restrict__ sSDE,
    const unsigned short* __restrict__ W1cT,
    const unsigned short* __restrict__ W2T,
    const float* __restrict__ b2,
    float* __restrict__ agg) {
    __shared__ float sY[64 * YS];            // 17408 B (aliased as sM later)
    __shared__ unsigned short sH[64 * KS];   // 9216 B
    __shared__ int sDst[64];
    __shared__ int sEid[64];
    float* sM = sY;

    int t = threadIdx.x;
    int lane = t & 63, w = t >> 6;
    int m = lane & 15, q = lane >> 4;

    // weight fragments (A-operands). Same addresses as B-pack layout.
    short8 w1c[4], w2f[2][4];
    #pragma unroll
    for (int tt = 0; tt < 4; tt++)
        w1c[tt] = *(const short8*)(W1cT + (tt * 16 + m) * 32 + q * 8);
    #pragma unroll
    for (int kt = 0; kt < 2; kt++)
        #pragma unroll
        for (int tt = 0; tt < 4; tt++)
            w2f[kt][tt] = *(const short8*)(W2T + (tt * 16 + m) * KS + kt * 32 + q * 8);

    // stage ysum = y1[src] + y2[dst] (fp32, vectorized) — 4 threads/edge
    {
        int eL = t >> 2, sub = t & 3;
        int gi = blockIdx.x * 64 + eL;
        int4 sde = sSDE[gi];
        if (sub == 0) { sDst[eL] = sde.y; sEid[eL] = sde.z; }
        const unsigned short* ys = yc + (size_t)sde.x * 128 + sub * 16;
        const unsigned short* yd = yc + (size_t)sde.y * 128 + 64 + sub * 16;
        short8 a0 = *(const short8*)(ys);
        short8 a1 = *(const short8*)(ys + 8);
        short8 d0 = *(const short8*)(yd);
        short8 d1 = *(const short8*)(yd + 8);
        float tmpv[16];
        #pragma unroll
        for (int j = 0; j < 8; j++) {
            tmpv[j]     = bf2f((unsigned short)a0[j]) + bf2f((unsigned short)d0[j]);
            tmpv[8 + j] = bf2f((unsigned short)a1[j]) + bf2f((unsigned short)d1[j]);
        }
        float4* o = (float4*)(sY + eL * YS + sub * 16);
        #pragma unroll
        for (int j = 0; j < 4; j++) o[j] = ((const float4*)tmpv)[j];
    }
    __syncthreads();

    int E = w * 16 + m;          // this lane's edge row within the 64-tile
    int e = sEid[E];

    // GEMM1 (K=32): C1' = (ea@W1c + b1)^T ; ea as B-operand, bias via 1.0
    short8 bf1 = {0, 0, 0, 0, 0, 0, 0, 0};
    if (q < 2) {
        const float4* p = (const float4*)(ea + (size_t)e * ED + q * 8);
        float4 v0 = p[0], v1 = p[1];
        bf1[0] = (short)f2bf(v0.x); bf1[1] = (short)f2bf(v0.y);
        bf1[2] = (short)f2bf(v0.z); bf1[3] = (short)f2bf(v0.w);
        bf1[4] = (short)f2bf(v1.x); bf1[5] = (short)f2bf(v1.y);
        bf1[6] = (short)f2bf(v1.z); bf1[7] = (short)f2bf(v1.w);
    } else if (q == 2) {
        bf1[0] = (short)0x3F80;   // k=16 -> multiplies b1 row
    }
    floatx4 acc[4];
    #pragma unroll
    for (int i = 0; i < 4; i++) acc[i] = (floatx4){0.f, 0.f, 0.f, 0.f};
    #pragma unroll
    for (int tt = 0; tt < 4; tt++)
        acc[tt] = __builtin_amdgcn_mfma_f32_16x16x32_bf16(w1c[tt], bf1, acc[tt], 0, 0, 0);

    // epi1: lane owns edge E, channels tt*16+q*4..+3 -> vector LDS ops
    #pragma unroll
    for (int tt = 0; tt < 4; tt++) {
        float4 ys4 = *(const float4*)(sY + E * YS + tt * 16 + q * 4);
        ushort4 hp;
        hp.x = f2bf(silu(acc[tt][0] + ys4.x));
        hp.y = f2bf(silu(acc[tt][1] + ys4.y));
        hp.z = f2bf(silu(acc[tt][2] + ys4.z));
        hp.w = f2bf(silu(acc[tt][3] + ys4.w));
        *(ushort4*)(sH + E * KS + tt * 16 + q * 4) = hp;
    }
    __syncthreads();   // sH visible; all sY reads done (sM aliasing safe)

    // GEMM2: C2' = (h@W2)^T ; h fragment as B-operand (same read as before)
    floatx4 acc2[4];
    #pragma unroll
    for (int i = 0; i < 4; i++) acc2[i] = (floatx4){0.f, 0.f, 0.f, 0.f};
    #pragma unroll
    for (int kt = 0; kt < 2; kt++) {
        short8 hfr = *(const short8*)(sH + E * KS + kt * 32 + q * 8);
        #pragma unroll
        for (int tt = 0; tt < 4; tt++)
            acc2[tt] = __builtin_amdgcn_mfma_f32_16x16x32_bf16(w2f[kt][tt], hfr, acc2[tt], 0, 0, 0);
    }

    // epi2: messages -> sM (fp32, vector stores; aliases sY)
    #pragma unroll
    for (int tt = 0; tt < 4; tt++) {
        float4 bb = *(const float4*)(b2 + tt * 16 + q * 4);
        float4 mv;
        mv.x = silu(acc2[tt][0] + bb.x);
        mv.y = silu(acc2[tt][1] + bb.y);
        mv.z = silu(acc2[tt][2] + bb.z);
        mv.w = silu(acc2[tt][3] + bb.w);
        *(float4*)(sM + E * YS + tt * 16 + q * 4) = mv;
    }
    __syncthreads();

    // segment-reduce: wave w reduces rows [w*16, w*16+16), lane = column
    {
        int c = lane;
        float s = 0.f;
        int cur = sDst[w * 16];
        #pragma unroll
        for (int r = 0; r < 16; r++) {
            int rr = w * 16 + r;
            int d = sDst[rr];
            if (d != cur) {
                atomicAdd(&agg[(size_t)cur * H + c], s);
                s = 0.f;
                cur = d;
            }
            s += sM[rr * YS + c];
        }
        atomicAdd(&agg[(size_t)cur * H + c], s);
    }
}

// ---- node MLP (transposed MFMA) ----------------------------------------
__global__ __launch_bounds__(256) void node_kernel(
    const unsigned short* __restrict__ xb,
    const float* __restrict__ agg,
    const unsigned short* __restrict__ W3T,
    const float* __restrict__ b3,
    float* __restrict__ out) {
    __shared__ unsigned short sW3[64 * K3S];
    __shared__ unsigned short sA[64 * K3S];

    int t = threadIdx.x;
    int n0 = blockIdx.x * 64;

    {
        const uint4* wv = (const uint4*)W3T;
        uint4* sv = (uint4*)sW3;
        for (int i = t; i < 64 * K3S * 2 / 16; i += 256) sv[i] = wv[i];
    }
    {
        int nL = t >> 2, sub = t & 3;
        int node = n0 + nL;
        uint4* arow = (uint4*)(sA + nL * K3S);
        if (node < NN) {
            const uint4* xs = (const uint4*)(xb + (size_t)node * H);
            arow[sub * 2]     = xs[sub * 2];
            arow[sub * 2 + 1] = xs[sub * 2 + 1];
            const float4* av = (const float4*)(agg + (size_t)node * H);
            unsigned short tmp[16];
            #pragma unroll
            for (int j = 0; j < 4; j++) {
                float4 v = av[sub * 4 + j];
                tmp[j * 4 + 0] = f2bf(v.x); tmp[j * 4 + 1] = f2bf(v.y);
                tmp[j * 4 + 2] = f2bf(v.z); tmp[j * 4 + 3] = f2bf(v.w);
            }
            uint4* drow = (uint4*)(sA + nL * K3S + 64 + sub * 16);
            drow[0] = ((const uint4*)tmp)[0];
            drow[1] = ((const uint4*)tmp)[1];
        } else {
            uint4 z = {0, 0, 0, 0};
            arow[sub * 2] = z; arow[sub * 2 + 1] = z;
            uint4* drow = (uint4*)(sA + nL * K3S + 64 + sub * 16);
            drow[0] = z; drow[1] = z;
        }
    }
    __syncthreads();

    int w = t >> 6, lane = t & 63;
    int m = lane & 15, q = lane >> 4;
    int node = n0 + w * 16 + m;   // this lane's node (B-operand col)

    floatx4 acc[4];
    #pragma unroll
    for (int i = 0; i < 4; i++) acc[i] = (floatx4){0.f, 0.f, 0.f, 0.f};
    #pragma unroll
    for (int kt = 0; kt < 4; kt++) {
        short8 bfr = *(const short8*)(sA + (w * 16 + m) * K3S + kt * 32 + q * 8);
        #pragma unroll
        for (int tt = 0; tt < 4; tt++) {
            short8 afr = *(const short8*)(sW3 + (tt * 16 + m) * K3S + kt * 32 + q * 8);
            acc[tt] = __builtin_amdgcn_mfma_f32_16x16x32_bf16(afr, bfr, acc[tt], 0, 0, 0);
        }
    }
    if (node < NN) {
        #pragma unroll
        for (int tt = 0; tt < 4; tt++) {
            float4 bb = *(const float4*)(b3 + tt * 16 + q * 4);
            float4 ov;
            ov.x = silu(acc[tt][0] + bb.x);
            ov.y = silu(acc[tt][1] + bb.y);
            ov.z = silu(acc[tt][2] + bb.z);
            ov.w = silu(acc[tt][3] + bb.w);
            *(float4*)(out + (size_t)node * H + tt * 16 + q * 4) = ov;
        }
    }
}

static inline size_t align256(size_t x) { return (x + 255) & ~(size_t)255; }

extern "C" void kernel_launch(void* const* d_in, const int* in_sizes, int n_in,
                              void* d_out, int out_size, void* d_ws, size_t ws_size,
                              hipStream_t stream) {
    const float* x  = (const float*)d_in[0];
    const int*   ei = (const int*)d_in[1];
    const float* ea = (const float*)d_in[2];
    const float* W1 = (const float*)d_in[3];
    const float* b1 = (const float*)d_in[4];
    const float* W2 = (const float*)d_in[5];
    const float* b2 = (const float*)d_in[6];
    const float* W3 = (const float*)d_in[7];
    const float* b3 = (const float*)d_in[8];
    float* out = (float*)d_out;

    char* ws = (char*)d_ws;
    size_t o = 0;
    float* agg = (float*)(ws + o);                    o = align256(o + (size_t)NN * H * 4);
    unsigned short* xb = (unsigned short*)(ws + o);   o = align256(o + (size_t)NN * H * 2);
    unsigned short* yc = (unsigned short*)(ws + o);   o = align256(o + (size_t)NN * 128 * 2);
    unsigned short* W1abT = (unsigned short*)(ws + o); o = align256(o + 128 * KS * 2);
    unsigned short* W1cT = (unsigned short*)(ws + o); o = align256(o + 64 * 32 * 2);
    unsigned short* W2T = (unsigned short*)(ws + o);  o = align256(o + 64 * KS * 2);
    unsigned short* W3T = (unsigned short*)(ws + o);  o = align256(o + 64 * K3S * 2);
    int* offs = (int*)(ws + o);                       o = align256(o + (size_t)NN * 4);
    int* bsums = (int*)(ws + o);                      o = align256(o + NB1 * 4);
    int* cnt = (int*)(ws + o);                        o = align256(o + (size_t)NN * 4);
    int4* sSDE = (int4*)(ws + o);                     o = align256(o + (size_t)NE * 16);

    int* cursor = cnt;

    hipMemsetAsync(agg, 0, (size_t)NN * H * sizeof(float), stream);
    hipMemsetAsync(cnt, 0, (size_t)NN * sizeof(int), stream);
    prep_kernel<<<2048, 256, 0, stream>>>(x, W1, b1, W2, W3, ei, xb, W1abT, W1cT, W2T, W3T, cnt);
    scan_block_kernel<<<NB1, 256, 0, stream>>>(cnt, offs, bsums);
    scan_sums_kernel<<<1, 512, 0, stream>>>(bsums);
    scan_add_kernel<<<NB1, 256, 0, stream>>>(offs, bsums, cursor);
    scatter_kernel<<<NE / 256, 256, 0, stream>>>(ei, cursor, sSDE);
    y12_kernel<<<NNB, 256, 0, stream>>>(xb, W1abT, yc);
    edge_kernel<<<NT, 256, 0, stream>>>(yc, ea, sSDE, W1cT, W2T, b2, agg);
    node_kernel<<<NNB, 256, 0, stream>>>(xb, agg, W3T, b3, out);
}